// Round 3
// baseline (1442.972 us; speedup 1.0000x reference)
//
#include <hip/hip_runtime.h>
#include <stdint.h>

typedef _Float16 f16;
typedef _Float16 f16x2 __attribute__((ext_vector_type(2)));
typedef _Float16 f16x8 __attribute__((ext_vector_type(8)));
typedef float f32x4 __attribute__((ext_vector_type(4)));

#define SEQ   512
#define BATCH 128
#define DIM   512
#define HID   256
#define G4    1024

typedef const __attribute__((address_space(1))) void* gas1p;
typedef __attribute__((address_space(3))) void* las3p;

__device__ __forceinline__ uint32_t pk2(float a, float b){
  return __builtin_bit_cast(uint32_t, __builtin_amdgcn_cvt_pkrtz(a, b));
}

__device__ __forceinline__ float fdot2u(uint32_t a, uint32_t b, float c){
#if __has_builtin(__builtin_amdgcn_fdot2)
  f16x2 A = __builtin_bit_cast(f16x2, a);
  f16x2 B = __builtin_bit_cast(f16x2, b);
  return __builtin_amdgcn_fdot2(A, B, c, false);
#else
  f16x2 A = __builtin_bit_cast(f16x2, a);
  f16x2 B = __builtin_bit_cast(f16x2, b);
  return c + (float)A.x*(float)B.x + (float)A.y*(float)B.y;
#endif
}

__device__ __forceinline__ float sigm(float x){
  return __builtin_amdgcn_rcpf(1.0f + __expf(-x));
}
__device__ __forceinline__ float tanh_(float x){
  return 1.0f - 2.0f*__builtin_amdgcn_rcpf(__expf(2.0f*x) + 1.0f);
}

// ---------------- phase 0: fp32 -> f16 convert (vectorized, 8 elems/thread) ----
__global__ void __launch_bounds__(256) cvt_f16_kernel(const float* __restrict__ in,
                                                      f16* __restrict__ out, int n8){
  int i = blockIdx.x*blockDim.x + threadIdx.x;
  if (i >= n8) return;
  const float4* p = (const float4*)in;
  float4 a = p[2*i], b = p[2*i+1];
  uint4 r;
  r.x = pk2(a.x, a.y); r.y = pk2(a.z, a.w);
  r.z = pk2(b.x, b.y); r.w = pk2(b.z, b.w);
  ((uint4*)out)[i] = r;
}

// ---------------- phase 0b: pack W_hh into f16 quads, layout [q][g] ------------
// Wgq[q*1024 + g] = f16x8 of Whh[g][8q .. 8q+8), q = 0..31, g = 0..1023.
__global__ void __launch_bounds__(256) prep_whh(const float* __restrict__ Whh,
                                                uint4* __restrict__ Wgq){
  int idx = blockIdx.x*256 + threadIdx.x;      // 0..32767
  int q = idx >> 10, g = idx & 1023;
  const float* wr = Whh + g*HID + 8*q;
  float4 v0 = *(const float4*)wr;
  float4 v1 = *(const float4*)(wr + 4);
  Wgq[idx] = make_uint4(pk2(v0.x,v0.y), pk2(v0.z,v0.w), pk2(v1.x,v1.y), pk2(v1.z,v1.w));
}

// ---------------- phase 1: xg[m][g] = A[m][:] . W[g][:] + bias[g]  (f16 MFMA) --
#define BM 128
#define BN 128
#define BK 64

__global__ void __launch_bounds__(256) gemm_xg_kernel(const f16* __restrict__ A,
                                                      const f16* __restrict__ Bm,
                                                      const float* __restrict__ bih,
                                                      const float* __restrict__ bhh,
                                                      f16* __restrict__ C){
  __shared__ __align__(16) f16 ldsA[BM*BK];
  __shared__ __align__(16) f16 ldsB[BN*BK];
  const int tid  = threadIdx.x;
  const int wave = tid >> 6;
  const int lane = tid & 63;
  const int bid  = blockIdx.x;
  const int nt   = bid & 7;
  const int mt   = bid >> 3;
  const long m0  = (long)mt * BM;
  const int n0   = nt * BN;
  const int wm   = wave >> 1, wn = wave & 1;
  const int lrow = lane >> 3;
  const int lk   = (lane & 7) * 8;

  f32x4 acc[4][4];
  #pragma unroll
  for (int i=0;i<4;++i)
    #pragma unroll
    for (int j=0;j<4;++j) acc[i][j] = (f32x4){0.f,0.f,0.f,0.f};

  auto ldsAq = (__attribute__((address_space(3))) char*)ldsA;
  auto ldsBq = (__attribute__((address_space(3))) char*)ldsB;

  for (int kt = 0; kt < DIM/BK; ++kt){
    const int k0 = kt*BK;
    __syncthreads();
    #pragma unroll
    for (int i = 0; i < 4; ++i){
      const int seg = wave*4 + i;
      const f16* ga = A  + (m0 + seg*8 + lrow)*DIM + (k0 + lk);
      const f16* gb = Bm + (long)(n0 + seg*8 + lrow)*DIM + (k0 + lk);
      __builtin_amdgcn_global_load_lds((gas1p)ga, (las3p)(ldsAq + seg*1024), 16, 0, 0);
      __builtin_amdgcn_global_load_lds((gas1p)gb, (las3p)(ldsBq + seg*1024), 16, 0, 0);
    }
    __syncthreads();
    #pragma unroll
    for (int kk = 0; kk < 2; ++kk){
      f16x8 af[4], bf[4];
      const int kb = kk*32 + (lane>>4)*8;
      #pragma unroll
      for (int mi=0; mi<4; ++mi){
        af[mi] = *(const f16x8*)(ldsA + (wm*64 + mi*16 + (lane&15))*BK + kb);
        bf[mi] = *(const f16x8*)(ldsB + (wn*64 + mi*16 + (lane&15))*BK + kb);
      }
      #pragma unroll
      for (int mi=0;mi<4;++mi)
        #pragma unroll
        for (int ni=0;ni<4;++ni)
          acc[mi][ni] = __builtin_amdgcn_mfma_f32_16x16x32_f16(af[mi], bf[ni], acc[mi][ni], 0,0,0);
    }
  }
  float bias[4];
  #pragma unroll
  for (int ni=0;ni<4;++ni){
    int col = n0 + wn*64 + ni*16 + (lane&15);
    bias[ni] = bih[col] + bhh[col];
  }
  #pragma unroll
  for (int mi=0;mi<4;++mi){
    #pragma unroll
    for (int ni=0;ni<4;++ni){
      int col = n0 + wn*64 + ni*16 + (lane&15);
      #pragma unroll
      for (int r=0;r<4;++r){
        long row = m0 + wm*64 + mi*16 + (lane>>4)*4 + r;
        C[row*G4 + col] = (f16)(acc[mi][ni][r] + bias[ni]);
      }
    }
  }
}

// ---------------- phase 2: sequential LSTM + fused FC head ---------------------
// 128 blocks x 512 threads, 1 block/CU. Thread t: gate rows t and t+512.
// Weights: k 64..255 in VGPRs (192 u32), k 0..31 from 64KB LDS slab,
// k 32..63 streamed from L2 (Wgq quads). h exchanged via per-block global
// buffer, read as uniform vector loads on the VMEM pipe (NOT the LDS pipe).
__global__ void __launch_bounds__(512, 1) lstm_kernel(const f16* __restrict__ xg,
                                                      const uint4* __restrict__ Wgq,
                                                      const float* __restrict__ fcw,
                                                      const float* __restrict__ fcb,
                                                      f16* __restrict__ hbase,
                                                      float* __restrict__ out){
  extern __shared__ __align__(16) char smem[];
  uint4* Wl4 = (uint4*)smem;               // [4][1024] uint4 = 64 KB (k 0..31)
  float* igx = (float*)(smem + 65536);     // 256 f32 exchange
  const int t  = threadIdx.x;
  const int b  = blockIdx.x;
  const int t2 = t + 512;

  // LDS slab = first 4096 quads of Wgq (q = 0..3), coalesced copy
  #pragma unroll
  for (int r = 0; r < 8; ++r) Wl4[r*512 + t] = Wgq[r*512 + t];

  // register weights: quads q = 8..31 (k 64..255) for both gate rows
  uint32_t w0[96], w1[96];
  #pragma unroll
  for (int q = 8; q < 32; ++q){
    uint4 a = Wgq[q*1024 + t];
    int o = (q-8)*4;
    w0[o+0]=a.x; w0[o+1]=a.y; w0[o+2]=a.z; w0[o+3]=a.w;
  }
  #pragma unroll
  for (int q = 8; q < 32; ++q){
    uint4 a = Wgq[q*1024 + t2];
    int o = (q-8)*4;
    w1[o+0]=a.x; w1[o+1]=a.y; w1[o+2]=a.z; w1[o+3]=a.w;
  }

  f16* hst = hbase + b*256;                // per-block h buffer (512 B, L1/L2-hot)
  if (t < 32) ((uint4*)hst)[t] = make_uint4(0,0,0,0);

  // opaque pointer: force VECTOR loads for the uniform-address h reads
  const uint4* hq = (const uint4*)hst;
  asm volatile("" : "+v"(hq));

  float c = 0.f, hlast = 0.f;
  __syncthreads();                          // covers LDS fill + h zero-init

  const f16* xrow = xg + (long)b * SEQ * G4;
  f16 pa = xrow[t], pb = xrow[t2];          // step-0 preload

  for (int ts = 0; ts < SEQ; ++ts){
    float acc0 = (float)pa, acc1 = (float)pb;
    if (ts + 1 < SEQ){
      pa = xrow[(ts+1)*G4 + t];
      pb = xrow[(ts+1)*G4 + t2];
    }
    // k 0..31 : LDS slab
    #pragma unroll
    for (int q = 0; q < 4; ++q){
      uint4 hv  = hq[q];
      uint4 wv0 = Wl4[q*1024 + t];
      uint4 wv1 = Wl4[q*1024 + t2];
      acc0 = fdot2u(wv0.x, hv.x, acc0);
      acc0 = fdot2u(wv0.y, hv.y, acc0);
      acc0 = fdot2u(wv0.z, hv.z, acc0);
      acc0 = fdot2u(wv0.w, hv.w, acc0);
      acc1 = fdot2u(wv1.x, hv.x, acc1);
      acc1 = fdot2u(wv1.y, hv.y, acc1);
      acc1 = fdot2u(wv1.z, hv.z, acc1);
      acc1 = fdot2u(wv1.w, hv.w, acc1);
    }
    // k 32..63 : streamed from L2
    #pragma unroll
    for (int q = 4; q < 8; ++q){
      uint4 hv  = hq[q];
      uint4 wv0 = Wgq[q*1024 + t];
      uint4 wv1 = Wgq[q*1024 + t2];
      acc0 = fdot2u(wv0.x, hv.x, acc0);
      acc0 = fdot2u(wv0.y, hv.y, acc0);
      acc0 = fdot2u(wv0.z, hv.z, acc0);
      acc0 = fdot2u(wv0.w, hv.w, acc0);
      acc1 = fdot2u(wv1.x, hv.x, acc1);
      acc1 = fdot2u(wv1.y, hv.y, acc1);
      acc1 = fdot2u(wv1.z, hv.z, acc1);
      acc1 = fdot2u(wv1.w, hv.w, acc1);
    }
    // k 64..255 : register-resident weights
    #pragma unroll
    for (int q = 8; q < 32; ++q){
      uint4 hv = hq[q];
      const int o = (q-8)*4;
      acc0 = fdot2u(w0[o+0], hv.x, acc0);
      acc0 = fdot2u(w0[o+1], hv.y, acc0);
      acc0 = fdot2u(w0[o+2], hv.z, acc0);
      acc0 = fdot2u(w0[o+3], hv.w, acc0);
      acc1 = fdot2u(w1[o+0], hv.x, acc1);
      acc1 = fdot2u(w1[o+1], hv.y, acc1);
      acc1 = fdot2u(w1[o+2], hv.z, acc1);
      acc1 = fdot2u(w1[o+3], hv.w, acc1);
    }
    // t<256: acc0=i, acc1=g.  t>=256: acc0=f, acc1=o (unit j = t-256).
    if (t < 256) igx[t] = sigm(acc0) * tanh_(acc1);
    __syncthreads();
    if (t >= 256){
      int j = t - 256;
      c     = sigm(acc0)*c + igx[j];
      hlast = sigm(acc1) * tanh_(c);
      hst[j] = (f16)hlast;                  // global store; visible via L1 + fence
    }
    __syncthreads();                        // drains vmcnt, publishes new h
  }
  // ---- fused FC head
  if (t >= 256) igx[t-256] = hlast;
  __syncthreads();
  if (t < 64){
    float s = 0.f;
    #pragma unroll
    for (int q=0;q<4;++q){ int j = t + 64*q; s += igx[j]*fcw[j]; }
    #pragma unroll
    for (int off=32; off; off>>=1) s += __shfl_down(s, off);
    if (t==0) out[b] = s + fcb[0];
  }
}

extern "C" void kernel_launch(void* const* d_in, const int* in_sizes, int n_in,
                              void* d_out, int out_size, void* d_ws, size_t ws_size,
                              hipStream_t stream) {
  const float* x   = (const float*)d_in[0];
  const float* Wih = (const float*)d_in[1];
  const float* Whh = (const float*)d_in[2];
  const float* bih = (const float*)d_in[3];
  const float* bhh = (const float*)d_in[4];
  const float* fcw = (const float*)d_in[5];
  const float* fcb = (const float*)d_in[6];
  float* out = (float*)d_out;

  char* ws = (char*)d_ws;
  f16*   xh   = (f16*)ws;                                  //  67,108,864 B
  f16*   Wh   = (f16*)(ws + 67108864);                     //   1,048,576 B
  f16*   xg   = (f16*)(ws + 68157440);                     // 134,217,728 B
  uint4* Wgq  = (uint4*)(ws + 202375168);                  //     524,288 B
  f16*   hbuf = (f16*)(ws + 202899456);                    //      65,536 B

  cvt_f16_kernel<<<16384, 256, 0, stream>>>(x,   xh, 33554432/8);
  cvt_f16_kernel<<<256,   256, 0, stream>>>(Wih, Wh, 524288/8);
  prep_whh<<<128, 256, 0, stream>>>(Whh, Wgq);
  gemm_xg_kernel<<<4096, 256, 0, stream>>>(xh, Wh, bih, bhh, xg);
  (void)hipFuncSetAttribute(reinterpret_cast<const void*>(lstm_kernel),
                            hipFuncAttributeMaxDynamicSharedMemorySize, 66560);
  lstm_kernel<<<BATCH, 512, 66560, stream>>>(xg, Wgq, fcw, fcb, hbuf, out);
}